// Round 1
// baseline (1761.622 us; speedup 1.0000x reference)
//
#include <hip/hip_runtime.h>
#include <stdint.h>

#define NUM_USERS 20000
#define EMBED_DIM 64
#define KTOP 6            // K+1
#define BLOCK 256
#define NWAVES (BLOCK / 64)

typedef unsigned long long u64;

// Insert (bits, idx) into the per-thread descending top-6 kept in named
// registers k0..k5. Common path rejects on a 32-bit compare (thrhi = hi32(k5)).
// key = (float_bits << 32) | (0xFFFFFFFF - idx): values in [0,1) so float
// bits order as unsigned; ties -> lower idx wins, matching lax.top_k.
#define PROC1(BITS, IDX)                                                      \
    do {                                                                      \
        unsigned _bits = (BITS);                                              \
        if (_bits >= thrhi) {                                                 \
            u64 _key = ((u64)_bits << 32) |                                   \
                       (u64)(0xFFFFFFFFu - (unsigned)(IDX));                  \
            if (_key > k5) {                                                  \
                k5 = _key;                                                    \
                u64 _t;                                                       \
                if (k5 > k4) { _t = k4; k4 = k5; k5 = _t; }                   \
                if (k4 > k3) { _t = k3; k3 = k4; k4 = _t; }                   \
                if (k3 > k2) { _t = k2; k2 = k3; k3 = _t; }                   \
                if (k2 > k1) { _t = k1; k1 = k2; k2 = _t; }                   \
                if (k1 > k0) { _t = k0; k0 = k1; k1 = _t; }                   \
                thrhi = (unsigned)(k5 >> 32);                                 \
            }                                                                 \
        }                                                                     \
    } while (0)

#define PROC4(V, BASE)                                                        \
    do {                                                                      \
        PROC1(__float_as_uint((V).x), (BASE) + 0);                            \
        PROC1(__float_as_uint((V).y), (BASE) + 1);                            \
        PROC1(__float_as_uint((V).z), (BASE) + 2);                            \
        PROC1(__float_as_uint((V).w), (BASE) + 3);                            \
    } while (0)

__global__ __launch_bounds__(BLOCK, 8) void topk_blend_kernel(
    const int* __restrict__ user_idx,
    const float* __restrict__ emb,
    const float* __restrict__ cooc,
    float* __restrict__ out)
{
    const int b    = blockIdx.x;
    const int tid  = threadIdx.x;
    const int lane = tid & 63;
    const int wave = tid >> 6;

    const int u = user_idx[b];
    // 64-bit offset: u*20000 floats up to 1.6e9 bytes -> no int32 math
    const float4* __restrict__ row4 =
        (const float4*)(cooc + (size_t)u * NUM_USERS);

    u64 k0 = 0, k1 = 0, k2 = 0, k3 = 0, k4 = 0, k5 = 0;
    unsigned thrhi = 0u;

    const int n4 = NUM_USERS / 4;          // 5000, exact

    // ---- scan: 4 independent float4 loads in flight per step (64 B/lane),
    // consume only after all are issued -> MLP instead of vmcnt(0)/iter ----
    int i = tid;
    for (; i + 3 * BLOCK < n4; i += 4 * BLOCK) {
        float4 va = row4[i];
        float4 vb = row4[i +     BLOCK];
        float4 vc = row4[i + 2 * BLOCK];
        float4 vd = row4[i + 3 * BLOCK];
        PROC4(va, 4 * i);
        PROC4(vb, 4 * (i +     BLOCK));
        PROC4(vc, 4 * (i + 2 * BLOCK));
        PROC4(vd, 4 * (i + 3 * BLOCK));
    }
    for (; i < n4; i += BLOCK) {
        float4 va = row4[i];
        PROC4(va, 4 * i);
    }

    // ---- wave-level merge: 6 rounds of butterfly max; per-thread list kept
    // in named registers with a predicated shift (no runtime indexing) ----
    __shared__ u64   s_wtop[NWAVES][KTOP];
    __shared__ int   s_idx[KTOP - 1];
    __shared__ float s_w[KTOP - 1];

    {
        u64 l0 = k0, l1 = k1, l2 = k2, l3 = k3, l4 = k4, l5 = k5;
        #pragma unroll
        for (int r = 0; r < KTOP; ++r) {
            u64 m = l0;
            #pragma unroll
            for (int off = 32; off > 0; off >>= 1) {
                u64 o = __shfl_xor(m, off, 64);
                if (o > m) m = o;
            }
            if (lane == 0) s_wtop[wave][r] = m;
            // keys are unique (idx embedded) -> exactly one owning lane
            if (l0 == m) { l0 = l1; l1 = l2; l2 = l3; l3 = l4; l4 = l5; l5 = 0; }
        }
    }
    __syncthreads();

    // ---- cross-wave 4-way merge of sorted lists + softmax (thread 0),
    // explicit scalar pointers p0..p3 (registers, no private arrays) ----
    if (tid == 0) {
        int p0 = 0, p1 = 0, p2 = 0, p3 = 0;
        u64 top[KTOP];                      // fully unrolled -> registers
        #pragma unroll
        for (int r = 0; r < KTOP; ++r) {
            // at round r each p <= r <= 5: in-bounds LDS reads
            u64 c0 = s_wtop[0][p0];
            u64 c1 = s_wtop[1][p1];
            u64 c2 = s_wtop[2][p2];
            u64 c3 = s_wtop[3][p3];
            u64 m01 = c0 > c1 ? c0 : c1;
            u64 m23 = c2 > c3 ? c2 : c3;
            u64 m   = m01 > m23 ? m01 : m23;
            top[r] = m;
            if      (m == c0) p0++;
            else if (m == c1) p1++;
            else if (m == c2) p2++;
            else              p3++;
        }
        // drop rank 0; softmax over vals[1..5] (sorted desc -> max is first)
        float vals[KTOP - 1];
        #pragma unroll
        for (int j = 0; j < KTOP - 1; ++j)
            vals[j] = __uint_as_float((unsigned)(top[j + 1] >> 32));
        float mx = vals[0];
        float e[KTOP - 1];
        float sum = 0.f;
        #pragma unroll
        for (int j = 0; j < KTOP - 1; ++j) { e[j] = expf(vals[j] - mx); sum += e[j]; }
        float inv = 1.f / sum;
        #pragma unroll
        for (int j = 0; j < KTOP - 1; ++j) {
            s_idx[j] = (int)(0xFFFFFFFFu - (unsigned)(top[j + 1] & 0xFFFFFFFFull));
            s_w[j]   = e[j] * inv;
        }
    }
    __syncthreads();

    // ---- gather 5 embeddings + blend; one thread per dim (coalesced 256B rows) ----
    if (tid < EMBED_DIM) {
        const int d = tid;
        float acc = 0.f;
        #pragma unroll
        for (int j = 0; j < KTOP - 1; ++j)
            acc += s_w[j] * emb[(size_t)s_idx[j] * EMBED_DIM + d];
        float own = emb[(size_t)u * EMBED_DIM + d];
        out[(size_t)b * EMBED_DIM + d] = 0.7f * own + 0.3f * acc;
    }
}

extern "C" void kernel_launch(void* const* d_in, const int* in_sizes, int n_in,
                              void* d_out, int out_size, void* d_ws, size_t ws_size,
                              hipStream_t stream) {
    const int*   user_idx = (const int*)d_in[0];
    const float* emb      = (const float*)d_in[1];
    const float* cooc     = (const float*)d_in[2];
    float*       out      = (float*)d_out;

    const int batch = in_sizes[0];   // 4096
    topk_blend_kernel<<<batch, BLOCK, 0, stream>>>(user_idx, emb, cooc, out);
}